// Round 4
// baseline (662.870 us; speedup 1.0000x reference)
//
#include <hip/hip_runtime.h>
#include <stdint.h>

typedef unsigned short u16;
typedef __attribute__((ext_vector_type(8))) short short8;
typedef __attribute__((ext_vector_type(4))) float f32x4;
typedef __attribute__((ext_vector_type(4))) unsigned short u16x4;

#define MFMA16(a, b, c) __builtin_amdgcn_mfma_f32_16x16x32_bf16((a), (b), (c), 0, 0, 0)

__device__ __forceinline__ float bf2f(u16 u) {
    union { uint32_t i; float f; } v;
    v.i = ((uint32_t)u) << 16;
    return v.f;
}
__device__ __forceinline__ u16 f2bf(float f) {  // round-to-nearest-even
    union { float f; uint32_t i; } v;
    v.f = f;
    uint32_t r = v.i + 0x7FFF + ((v.i >> 16) & 1);
    return (u16)(r >> 16);
}
__device__ __forceinline__ float scrub(float x) {  // bit-level Inf/NaN scrub
    union { float f; uint32_t i; } v;
    v.f = x;
    return ((v.i & 0x7F800000u) == 0x7F800000u) ? 0.f : x;
}
// Permuted Srel offset: consumer lane (g=(q>>2)&3, cc=k&15) of wave w=(q>>4)&3,
// qtile q>>6, kt=k>>7 reads 32 contiguous u16 indexed [nt=(k>>4)&7][r=q&3].
__device__ __forceinline__ int soff(int q, int k) {
    return ((q >> 4) << 14) | ((k >> 7) << 11) | ((q & 12) << 7) |
           ((k & 15) << 5) | ((k & 112) >> 2) | (q & 3);
}

// ---------------------------------------------------------------------------
// Transpose 4 fp32 weight matrices (1024x1024) -> bf16 Wt[n][k] = W[k][n]
// ---------------------------------------------------------------------------
__global__ __launch_bounds__(256) void transpose4(
    const float* __restrict__ W0, const float* __restrict__ W1,
    const float* __restrict__ W2, const float* __restrict__ W3,
    u16* __restrict__ out)
{
    __shared__ u16 t[32][33];
    int z = blockIdx.z;
    const float* W = (z == 0) ? W0 : (z == 1) ? W1 : (z == 2) ? W2 : W3;
    u16* o = out + (size_t)z * 1048576;
    int tx = threadIdx.x & 31, ty = threadIdx.x >> 5;
    int x = blockIdx.x * 32 + tx;
    int yb = blockIdx.y * 32;
#pragma unroll
    for (int j = 0; j < 4; j++)
        t[ty + j * 8][tx] = f2bf(W[(size_t)(yb + ty + j * 8) * 1024 + x]);
    __syncthreads();
    int xo = yb + tx;
    int yob = blockIdx.x * 32;
#pragma unroll
    for (int j = 0; j < 4; j++)
        o[(size_t)(yob + ty + j * 8) * 1024 + xo] = t[tx][ty + j * 8];
}

// ---------------------------------------------------------------------------
// Merged K/V/Q projection GEMM: grid (8, 32, 3) -> 768 blocks (3/CU).
// C(M,N) = A(M,K)*Wt_z(N,K)^T + bias_z.  128x128 tile, 4 waves.
// z==1 (V): out (b,h,d,l); else (b,h,l,d).
// ---------------------------------------------------------------------------
__global__ __launch_bounds__(256) void gemm_qkv(
    const float* __restrict__ A0, const float* __restrict__ A1,
    const float* __restrict__ A2, const u16* __restrict__ Wt,
    const float* __restrict__ bi0, const float* __restrict__ bi1,
    const float* __restrict__ bi2, u16* __restrict__ khp,
    u16* __restrict__ vhtp, u16* __restrict__ qhp)
{
    __shared__ u16 As[128][40];
    __shared__ u16 Bs[128][40];
    const int K = 1024;
    int z = blockIdx.z;
    const float* A = (z == 0) ? A0 : (z == 1) ? A1 : A2;
    const float* bias = (z == 0) ? bi0 : (z == 1) ? bi1 : bi2;
    const u16* Bt = Wt + (size_t)z * 1048576;
    u16* outb = (z == 0) ? khp : (z == 1) ? vhtp : qhp;

    int n0 = blockIdx.x * 128, m0 = blockIdx.y * 128;
    int tid = threadIdx.x;
    int w = tid >> 6, lane = tid & 63, g = lane >> 4, cc = lane & 15;
    int wm = (w >> 1) * 64, wn = (w & 1) * 64;
    int tr = tid >> 2, tc = (tid & 3) * 8;
    int ar = tid >> 3, ac = (tid & 7) * 4;

    f32x4 acc[4][4];
#pragma unroll
    for (int i = 0; i < 4; i++)
#pragma unroll
        for (int j = 0; j < 4; j++) acc[i][j] = (f32x4){0.f, 0.f, 0.f, 0.f};

    for (int kb = 0; kb < K; kb += 32) {
        f32x4 av[4];
#pragma unroll
        for (int rr = 0; rr < 4; rr++)
            av[rr] = *(const f32x4*)&A[(size_t)(m0 + rr * 32 + ar) * K + kb + ac];
        short8 b0 = *(const short8*)&Bt[(size_t)(n0 + tr) * K + kb + tc];
        short8 b1 = *(const short8*)&Bt[(size_t)(n0 + 64 + tr) * K + kb + tc];
        __syncthreads();
#pragma unroll
        for (int rr = 0; rr < 4; rr++) {
            u16x4 ap;
#pragma unroll
            for (int r = 0; r < 4; r++) ap[r] = f2bf(av[rr][r]);
            *(u16x4*)&As[rr * 32 + ar][ac] = ap;
        }
        *(short8*)&Bs[tr][tc] = b0;
        *(short8*)&Bs[64 + tr][tc] = b1;
        __syncthreads();
        short8 af[4], bf[4];
#pragma unroll
        for (int mt = 0; mt < 4; mt++) af[mt] = *(const short8*)&As[wm + mt * 16 + cc][g * 8];
#pragma unroll
        for (int nt = 0; nt < 4; nt++) bf[nt] = *(const short8*)&Bs[wn + nt * 16 + cc][g * 8];
#pragma unroll
        for (int mt = 0; mt < 4; mt++)
#pragma unroll
            for (int nt = 0; nt < 4; nt++)
                acc[mt][nt] = MFMA16(af[mt], bf[nt], acc[mt][nt]);
    }

#pragma unroll
    for (int mt = 0; mt < 4; mt++) {
        int rl = wm + mt * 16 + g * 4;
#pragma unroll
        for (int nt = 0; nt < 4; nt++) {
            int n = n0 + wn + nt * 16 + cc;
            float bb = bias[n];
            if (z == 1) {  // V: (b,h,d,l)
                int m = m0 + rl;
                int b_ = m >> 10, l_ = m & 1023, h_ = n >> 6, d_ = n & 63;
                u16x4 pk;
#pragma unroll
                for (int r = 0; r < 4; r++) pk[r] = f2bf(scrub(acc[mt][nt][r] + bb));
                *(u16x4*)&outb[((size_t)(b_ * 16 + h_) * 64 + d_) * 1024 + l_] = pk;
            } else {  // K/Q: (b,h,l,d)
#pragma unroll
                for (int r = 0; r < 4; r++) {
                    int m = m0 + rl + r;
                    int b_ = m >> 10, l_ = m & 1023, h_ = n >> 6, d_ = n & 63;
                    outb[((size_t)(b_ * 16 + h_) * 1024 + l_) * 64 + d_] =
                        f2bf(scrub(acc[mt][nt][r] + bb));
                }
            }
        }
    }
}

// ---------------------------------------------------------------------------
// Final GEMM: out(4096,1024) = ctx(4096,1024)*Wo^T + bo.  64x128 tiles,
// grid (8, 64) -> 512 blocks (2/CU).  Waves 2x2, wave tile 32x64.
// ---------------------------------------------------------------------------
__global__ __launch_bounds__(256) void gemm_out(
    const float* __restrict__ A, const u16* __restrict__ Bt,
    const float* __restrict__ bias, float* __restrict__ outf)
{
    __shared__ u16 As[64][40];
    __shared__ u16 Bs[128][40];
    const int K = 1024;
    int n0 = blockIdx.x * 128, m0 = blockIdx.y * 64;
    int tid = threadIdx.x;
    int w = tid >> 6, lane = tid & 63, g = lane >> 4, cc = lane & 15;
    int wm = (w >> 1) * 32, wn = (w & 1) * 64;
    int tr = tid >> 2, tc = (tid & 3) * 8;
    int ar = tid >> 3, ac = (tid & 7) * 4;

    f32x4 acc[2][4];
#pragma unroll
    for (int i = 0; i < 2; i++)
#pragma unroll
        for (int j = 0; j < 4; j++) acc[i][j] = (f32x4){0.f, 0.f, 0.f, 0.f};

    for (int kb = 0; kb < K; kb += 32) {
        f32x4 av0 = *(const f32x4*)&A[(size_t)(m0 + ar) * K + kb + ac];
        f32x4 av1 = *(const f32x4*)&A[(size_t)(m0 + 32 + ar) * K + kb + ac];
        short8 b0 = *(const short8*)&Bt[(size_t)(n0 + tr) * K + kb + tc];
        short8 b1 = *(const short8*)&Bt[(size_t)(n0 + 64 + tr) * K + kb + tc];
        __syncthreads();
        u16x4 ap0, ap1;
#pragma unroll
        for (int r = 0; r < 4; r++) { ap0[r] = f2bf(av0[r]); ap1[r] = f2bf(av1[r]); }
        *(u16x4*)&As[ar][ac] = ap0;
        *(u16x4*)&As[32 + ar][ac] = ap1;
        *(short8*)&Bs[tr][tc] = b0;
        *(short8*)&Bs[64 + tr][tc] = b1;
        __syncthreads();
        short8 af[2], bf[4];
#pragma unroll
        for (int mt = 0; mt < 2; mt++) af[mt] = *(const short8*)&As[wm + mt * 16 + cc][g * 8];
#pragma unroll
        for (int nt = 0; nt < 4; nt++) bf[nt] = *(const short8*)&Bs[wn + nt * 16 + cc][g * 8];
#pragma unroll
        for (int mt = 0; mt < 2; mt++)
#pragma unroll
            for (int nt = 0; nt < 4; nt++)
                acc[mt][nt] = MFMA16(af[mt], bf[nt], acc[mt][nt]);
    }

#pragma unroll
    for (int mt = 0; mt < 2; mt++) {
        int rl = wm + mt * 16 + g * 4;
#pragma unroll
        for (int nt = 0; nt < 4; nt++) {
            int n = n0 + wn + nt * 16 + cc;
            float bb = bias[n];
#pragma unroll
            for (int r = 0; r < 4; r++)
                outf[(size_t)(m0 + rl + r) * 1024 + n] = scrub(acc[mt][nt][r] + bb);
        }
    }
}

// ---------------------------------------------------------------------------
// QE = qh_bh (1024x64) * e(1024x64 fp32->bf16)^T, scattered into PERMUTED
// Srel via the inverse skew (each (q,k) cell written exactly once):
//   B: (q=qi,   k=qi+mm-1023)  if k>=0          val = QE*(mm<=qi)
//   D: (q=qi,   k=qi+1)        if mm==1023,qi<1023   0
//   A: (q=qi-1, k=mm+qi+1)     if qi>=1, k<=1023     val
// ---------------------------------------------------------------------------
__global__ __launch_bounds__(256) void qe_srel(
    const u16* __restrict__ qh, const float* __restrict__ e, u16* __restrict__ SrelP)
{
    __shared__ u16 As[128][40];
    __shared__ u16 Bs[128][40];
    int mb = blockIdx.x * 128;
    int qb = blockIdx.y * 128;
    int bh = blockIdx.z;
    const u16* A = qh + (size_t)bh * 65536;
    u16* S = SrelP + (size_t)bh * 1048576;
    int tid = threadIdx.x;
    int w = tid >> 6, lane = tid & 63, g = lane >> 4, cc = lane & 15;
    int wm = (w >> 1) * 64, wn = (w & 1) * 64;
    int tr = tid >> 2, tc = (tid & 3) * 8;
    int ar = tid >> 3, ac = (tid & 7) * 4;

    f32x4 acc[4][4];
#pragma unroll
    for (int i = 0; i < 4; i++)
#pragma unroll
        for (int j = 0; j < 4; j++) acc[i][j] = (f32x4){0.f, 0.f, 0.f, 0.f};

    for (int kb = 0; kb < 64; kb += 32) {
        short8 a0 = *(const short8*)&A[(size_t)(qb + tr) * 64 + kb + tc];
        short8 a1 = *(const short8*)&A[(size_t)(qb + 64 + tr) * 64 + kb + tc];
        f32x4 bv[4];
#pragma unroll
        for (int rr = 0; rr < 4; rr++)
            bv[rr] = *(const f32x4*)&e[(size_t)(mb + rr * 32 + ar) * 64 + kb + ac];
        __syncthreads();
        *(short8*)&As[tr][tc] = a0;
        *(short8*)&As[64 + tr][tc] = a1;
#pragma unroll
        for (int rr = 0; rr < 4; rr++) {
            u16x4 bp;
#pragma unroll
            for (int r = 0; r < 4; r++) bp[r] = f2bf(bv[rr][r]);
            *(u16x4*)&Bs[rr * 32 + ar][ac] = bp;
        }
        __syncthreads();
        short8 af[4], bf[4];
#pragma unroll
        for (int mt = 0; mt < 4; mt++) af[mt] = *(const short8*)&As[wm + mt * 16 + cc][g * 8];
#pragma unroll
        for (int nt = 0; nt < 4; nt++) bf[nt] = *(const short8*)&Bs[wn + nt * 16 + cc][g * 8];
#pragma unroll
        for (int mt = 0; mt < 4; mt++)
#pragma unroll
            for (int nt = 0; nt < 4; nt++)
                acc[mt][nt] = MFMA16(af[mt], bf[nt], acc[mt][nt]);
    }

#pragma unroll
    for (int mt = 0; mt < 4; mt++)
#pragma unroll
        for (int nt = 0; nt < 4; nt++)
#pragma unroll
            for (int r = 0; r < 4; r++) {
                int qi = qb + wm + mt * 16 + g * 4 + r;
                int mm = mb + wn + nt * 16 + cc;
                u16 bv_ = (mm <= qi) ? f2bf(scrub(acc[mt][nt][r])) : (u16)0;
                int k = qi + mm - 1023;
                if (k >= 0) S[soff(qi, k)] = bv_;
                if (mm == 1023 && qi < 1023) S[soff(qi, qi + 1)] = (u16)0;
                int k2 = mm + qi + 1;
                if (qi >= 1 && k2 <= 1023) S[soff(qi - 1, k2)] = bv_;
            }
}

// ---------------------------------------------------------------------------
// Flash attention: grid (16, 64) -> 1024 blocks (4/CU).  Block = 64 Q-rows,
// each wave owns 16.  No barriers (Plds is wave-private).  Srel gathered
// from the permuted layout with 4 coalesced 16B loads per lane per K-tile.
// ---------------------------------------------------------------------------
__global__ __launch_bounds__(256) void flash(
    const u16* __restrict__ qh, const u16* __restrict__ kh,
    const u16* __restrict__ vht, const u16* __restrict__ SrelP,
    float* __restrict__ ctx)
{
    __shared__ u16 Plds[4][16][136];
    int qt = blockIdx.x, bh = blockIdx.y;
    int w = threadIdx.x >> 6, lane = threadIdx.x & 63, g = lane >> 4, cc = lane & 15;
    const u16* Q = qh + (size_t)bh * 65536;
    const u16* Kp = kh + (size_t)bh * 65536;
    const u16* Vp = vht + (size_t)bh * 65536;
    // chunk base for kt=0; advances by 2048 u16 per kt
    const u16* Sp = SrelP + (size_t)bh * 1048576 +
                    ((size_t)(((qt * 4 + w) * 32 + g) * 16 + cc)) * 32;
    int q0 = qt * 64 + w * 16;

    short8 qf[2];
#pragma unroll
    for (int ks = 0; ks < 2; ks++)
        qf[ks] = *(const short8*)&Q[(size_t)(q0 + cc) * 64 + ks * 32 + g * 8];

    float mi[4], li[4];
    f32x4 O[4];
#pragma unroll
    for (int r = 0; r < 4; r++) { mi[r] = -1e30f; li[r] = 0.f; }
#pragma unroll
    for (int d = 0; d < 4; d++) O[d] = (f32x4){0.f, 0.f, 0.f, 0.f};

    const float LOG2E = 1.44269504088896f;

    for (int kt = 0; kt < 8; kt++) {
        int k0 = kt * 128;
        // prefetch Srel chunk (independent of MFMAs below)
        u16 cv[32];
        *(short8*)&cv[0]  = *(const short8*)&Sp[kt * 2048 + 0];
        *(short8*)&cv[8]  = *(const short8*)&Sp[kt * 2048 + 8];
        *(short8*)&cv[16] = *(const short8*)&Sp[kt * 2048 + 16];
        *(short8*)&cv[24] = *(const short8*)&Sp[kt * 2048 + 24];

        f32x4 sc[8];
#pragma unroll
        for (int nt = 0; nt < 8; nt++) sc[nt] = (f32x4){0.f, 0.f, 0.f, 0.f};
#pragma unroll
        for (int nt = 0; nt < 8; nt++) {
            short8 b0 = *(const short8*)&Kp[(size_t)(k0 + nt * 16 + cc) * 64 + g * 8];
            short8 b1 = *(const short8*)&Kp[(size_t)(k0 + nt * 16 + cc) * 64 + 32 + g * 8];
            sc[nt] = MFMA16(qf[0], b0, sc[nt]);
            sc[nt] = MFMA16(qf[1], b1, sc[nt]);
        }

#pragma unroll
        for (int nt = 0; nt < 8; nt++)
#pragma unroll
            for (int r = 0; r < 4; r++)
                sc[nt][r] = (sc[nt][r] + bf2f(cv[nt * 4 + r])) * 0.125f;

#pragma unroll
        for (int r = 0; r < 4; r++) {
            float mx = sc[0][r];
#pragma unroll
            for (int nt = 1; nt < 8; nt++) mx = fmaxf(mx, sc[nt][r]);
            mx = fmaxf(mx, __shfl_xor(mx, 1));
            mx = fmaxf(mx, __shfl_xor(mx, 2));
            mx = fmaxf(mx, __shfl_xor(mx, 4));
            mx = fmaxf(mx, __shfl_xor(mx, 8));
            float mnew = fmaxf(mi[r], mx);
            float alpha = exp2f((mi[r] - mnew) * LOG2E);
            mi[r] = mnew;
            float rs = 0.f;
#pragma unroll
            for (int nt = 0; nt < 8; nt++) {
                float p = exp2f((sc[nt][r] - mnew) * LOG2E);
                sc[nt][r] = p;
                rs += p;
            }
            rs += __shfl_xor(rs, 1);
            rs += __shfl_xor(rs, 2);
            rs += __shfl_xor(rs, 4);
            rs += __shfl_xor(rs, 8);
            li[r] = li[r] * alpha + rs;
#pragma unroll
            for (int d = 0; d < 4; d++) O[d][r] *= alpha;
        }

        // P: C-layout regs -> wave-private LDS (same-wave ordering via lgkmcnt)
#pragma unroll
        for (int nt = 0; nt < 8; nt++)
#pragma unroll
            for (int r = 0; r < 4; r++)
                Plds[w][g * 4 + r][nt * 16 + cc] = f2bf(sc[nt][r]);

#pragma unroll
        for (int ks = 0; ks < 4; ks++) {
            short8 a = *(const short8*)&Plds[w][cc][ks * 32 + g * 8];
#pragma unroll
            for (int d = 0; d < 4; d++) {
                short8 vb = *(const short8*)&Vp[(size_t)(d * 16 + cc) * 1024 + k0 + ks * 32 + g * 8];
                O[d] = MFMA16(a, vb, O[d]);
            }
        }
    }

    int b_ = bh >> 4, h_ = bh & 15;
#pragma unroll
    for (int d = 0; d < 4; d++)
#pragma unroll
        for (int r = 0; r < 4; r++) {
            int l_ = q0 + g * 4 + r;
            ctx[((size_t)b_ * 1024 + l_) * 1024 + h_ * 64 + d * 16 + cc] =
                O[d][r] / li[r];
        }
}

// ---------------------------------------------------------------------------
extern "C" void kernel_launch(void* const* d_in, const int* in_sizes, int n_in,
                              void* d_out, int out_size, void* d_ws, size_t ws_size,
                              hipStream_t stream)
{
    // Identify fp32 inputs by SIZE (robust to the bool mask's representation).
    const float *k_in = nullptr, *v_in = nullptr, *q_in = nullptr, *E = nullptr;
    const float* W[4] = {nullptr, nullptr, nullptr, nullptr};
    const float* bs[4] = {nullptr, nullptr, nullptr, nullptr};
    int nqkv = 0, nW = 0, nb = 0;
    for (int i = 0; i < n_in; i++) {
        int s = in_sizes[i];
        const float* p = (const float*)d_in[i];
        if (s == 4194304) {
            if (nqkv == 0) k_in = p; else if (nqkv == 1) v_in = p; else if (nqkv == 2) q_in = p;
            nqkv++;
        } else if (s == 131072) {
            E = p;
        } else if (s == 1048576) {
            if (nW < 4) W[nW] = p;
            nW++;
        } else if (s == 1024) {
            if (nb < 4) bs[nb] = p;
            nb++;
        }
    }

    char* ws = (char*)d_ws;
    u16*   Wt   = (u16*)ws;                        // 8 MB
    u16*   khp  = (u16*)(ws + (8u << 20));         // 8 MB  (b,h,l,d)
    u16*   vhtp = (u16*)(ws + (16u << 20));        // 8 MB  (b,h,d,l)
    u16*   qhp  = (u16*)(ws + (24u << 20));        // 8 MB  (b,h,l,d)
    float* ctxp = (float*)(ws + (32u << 20));      // 16 MB (b,l,h*d) fp32
    u16*   Srel = (u16*)(ws + (48u << 20));        // 128 MB permuted -> 176 MB

    const size_t M1 = 1048576;
    transpose4<<<dim3(32, 32, 4), 256, 0, stream>>>(W[0], W[1], W[2], W[3], Wt);
    gemm_qkv<<<dim3(8, 32, 3), 256, 0, stream>>>(k_in, v_in, q_in, Wt,
                                                 bs[0], bs[1], bs[2],
                                                 khp, vhtp, qhp);
    qe_srel<<<dim3(8, 8, 64), 256, 0, stream>>>(qhp, E + 1024 * 64, Srel);
    flash<<<dim3(16, 64), 256, 0, stream>>>(qhp, khp, vhtp, Srel, ctxp);
    gemm_out<<<dim3(8, 64), 256, 0, stream>>>(ctxp, Wt + 3 * M1, bs[3], (float*)d_out);
}

// Round 5
// 648.026 us; speedup vs baseline: 1.0229x; 1.0229x over previous
//
#include <hip/hip_runtime.h>
#include <stdint.h>

typedef unsigned short u16;
typedef __attribute__((ext_vector_type(8))) short short8;
typedef __attribute__((ext_vector_type(4))) float f32x4;
typedef __attribute__((ext_vector_type(4))) unsigned short u16x4;

#define MFMA16(a, b, c) __builtin_amdgcn_mfma_f32_16x16x32_bf16((a), (b), (c), 0, 0, 0)

__device__ __forceinline__ float bf2f(u16 u) {
    union { uint32_t i; float f; } v;
    v.i = ((uint32_t)u) << 16;
    return v.f;
}
__device__ __forceinline__ u16 f2bf(float f) {  // round-to-nearest-even
    union { float f; uint32_t i; } v;
    v.f = f;
    uint32_t r = v.i + 0x7FFF + ((v.i >> 16) & 1);
    return (u16)(r >> 16);
}
__device__ __forceinline__ float scrub(float x) {  // bit-level Inf/NaN scrub
    union { float f; uint32_t i; } v;
    v.f = x;
    return ((v.i & 0x7F800000u) == 0x7F800000u) ? 0.f : x;
}

// ---------------------------------------------------------------------------
// Transpose 4 fp32 weight matrices (1024x1024) -> bf16 Wt[n][k] = W[k][n]
// ---------------------------------------------------------------------------
__global__ __launch_bounds__(256) void transpose4(
    const float* __restrict__ W0, const float* __restrict__ W1,
    const float* __restrict__ W2, const float* __restrict__ W3,
    u16* __restrict__ out)
{
    __shared__ u16 t[32][33];
    int z = blockIdx.z;
    const float* W = (z == 0) ? W0 : (z == 1) ? W1 : (z == 2) ? W2 : W3;
    u16* o = out + (size_t)z * 1048576;
    int tx = threadIdx.x & 31, ty = threadIdx.x >> 5;
    int x = blockIdx.x * 32 + tx;
    int yb = blockIdx.y * 32;
#pragma unroll
    for (int j = 0; j < 4; j++)
        t[ty + j * 8][tx] = f2bf(W[(size_t)(yb + ty + j * 8) * 1024 + x]);
    __syncthreads();
    int xo = yb + tx;
    int yob = blockIdx.x * 32;
#pragma unroll
    for (int j = 0; j < 4; j++)
        o[(size_t)(yob + ty + j * 8) * 1024 + xo] = t[tx][ty + j * 8];
}

// ---------------------------------------------------------------------------
// Convert the live slice of E (1024x64 fp32) to bf16 once.
// ---------------------------------------------------------------------------
__global__ __launch_bounds__(256) void ecvt(
    const float* __restrict__ e, u16* __restrict__ eb)
{
    int i = (blockIdx.x * 256 + threadIdx.x) * 4;
    f32x4 v = *(const f32x4*)&e[i];
    u16x4 o;
#pragma unroll
    for (int r = 0; r < 4; r++) o[r] = f2bf(v[r]);
    *(u16x4*)&eb[i] = o;
}

// ---------------------------------------------------------------------------
// Merged K/V/Q projection GEMM: grid (8, 32, 3).
// C(M,N) = A(M,K)*Wt_z(N,K)^T + bias_z.  128x128 tile, 4 waves.
// z==1 (V): out (b,h,d,l); else (b,h,l,d).
// ---------------------------------------------------------------------------
__global__ __launch_bounds__(256) void gemm_qkv(
    const float* __restrict__ A0, const float* __restrict__ A1,
    const float* __restrict__ A2, const u16* __restrict__ Wt,
    const float* __restrict__ bi0, const float* __restrict__ bi1,
    const float* __restrict__ bi2, u16* __restrict__ khp,
    u16* __restrict__ vhtp, u16* __restrict__ qhp)
{
    __shared__ u16 As[128][40];
    __shared__ u16 Bs[128][40];
    const int K = 1024;
    int z = blockIdx.z;
    const float* A = (z == 0) ? A0 : (z == 1) ? A1 : A2;
    const float* bias = (z == 0) ? bi0 : (z == 1) ? bi1 : bi2;
    const u16* Bt = Wt + (size_t)z * 1048576;
    u16* outb = (z == 0) ? khp : (z == 1) ? vhtp : qhp;

    int n0 = blockIdx.x * 128, m0 = blockIdx.y * 128;
    int tid = threadIdx.x;
    int w = tid >> 6, lane = tid & 63, g = lane >> 4, cc = lane & 15;
    int wm = (w >> 1) * 64, wn = (w & 1) * 64;
    int tr = tid >> 2, tc = (tid & 3) * 8;
    int ar = tid >> 3, ac = (tid & 7) * 4;

    f32x4 acc[4][4];
#pragma unroll
    for (int i = 0; i < 4; i++)
#pragma unroll
        for (int j = 0; j < 4; j++) acc[i][j] = (f32x4){0.f, 0.f, 0.f, 0.f};

    for (int kb = 0; kb < K; kb += 32) {
        f32x4 av[4];
#pragma unroll
        for (int rr = 0; rr < 4; rr++)
            av[rr] = *(const f32x4*)&A[(size_t)(m0 + rr * 32 + ar) * K + kb + ac];
        short8 b0 = *(const short8*)&Bt[(size_t)(n0 + tr) * K + kb + tc];
        short8 b1 = *(const short8*)&Bt[(size_t)(n0 + 64 + tr) * K + kb + tc];
        __syncthreads();
#pragma unroll
        for (int rr = 0; rr < 4; rr++) {
            u16x4 ap;
#pragma unroll
            for (int r = 0; r < 4; r++) ap[r] = f2bf(av[rr][r]);
            *(u16x4*)&As[rr * 32 + ar][ac] = ap;
        }
        *(short8*)&Bs[tr][tc] = b0;
        *(short8*)&Bs[64 + tr][tc] = b1;
        __syncthreads();
        short8 af[4], bf[4];
#pragma unroll
        for (int mt = 0; mt < 4; mt++) af[mt] = *(const short8*)&As[wm + mt * 16 + cc][g * 8];
#pragma unroll
        for (int nt = 0; nt < 4; nt++) bf[nt] = *(const short8*)&Bs[wn + nt * 16 + cc][g * 8];
#pragma unroll
        for (int mt = 0; mt < 4; mt++)
#pragma unroll
            for (int nt = 0; nt < 4; nt++)
                acc[mt][nt] = MFMA16(af[mt], bf[nt], acc[mt][nt]);
    }

#pragma unroll
    for (int mt = 0; mt < 4; mt++) {
        int rl = wm + mt * 16 + g * 4;
#pragma unroll
        for (int nt = 0; nt < 4; nt++) {
            int n = n0 + wn + nt * 16 + cc;
            float bb = bias[n];
            if (z == 1) {  // V: (b,h,d,l)
                int m = m0 + rl;
                int b_ = m >> 10, l_ = m & 1023, h_ = n >> 6, d_ = n & 63;
                u16x4 pk;
#pragma unroll
                for (int r = 0; r < 4; r++) pk[r] = f2bf(scrub(acc[mt][nt][r] + bb));
                *(u16x4*)&outb[((size_t)(b_ * 16 + h_) * 64 + d_) * 1024 + l_] = pk;
            } else {  // K/Q: (b,h,l,d)
#pragma unroll
                for (int r = 0; r < 4; r++) {
                    int m = m0 + rl + r;
                    int b_ = m >> 10, l_ = m & 1023, h_ = n >> 6, d_ = n & 63;
                    outb[((size_t)(b_ * 16 + h_) * 1024 + l_) * 64 + d_] =
                        f2bf(scrub(acc[mt][nt][r] + bb));
                }
            }
        }
    }
}

// ---------------------------------------------------------------------------
// Final GEMM: out(4096,1024) = ctx(4096,1024 bf16)*Wo^T + bo.  64x128 tiles,
// grid (8, 64).  Waves 2x2, wave tile 32x64.  fp32 output.
// ---------------------------------------------------------------------------
__global__ __launch_bounds__(256) void gemm_out(
    const u16* __restrict__ A, const u16* __restrict__ Bt,
    const float* __restrict__ bias, float* __restrict__ outf)
{
    __shared__ u16 As[64][40];
    __shared__ u16 Bs[128][40];
    const int K = 1024;
    int n0 = blockIdx.x * 128, m0 = blockIdx.y * 64;
    int tid = threadIdx.x;
    int w = tid >> 6, lane = tid & 63, g = lane >> 4, cc = lane & 15;
    int wm = (w >> 1) * 32, wn = (w & 1) * 64;
    int tr = tid >> 2, tc = (tid & 3) * 8;

    f32x4 acc[2][4];
#pragma unroll
    for (int i = 0; i < 2; i++)
#pragma unroll
        for (int j = 0; j < 4; j++) acc[i][j] = (f32x4){0.f, 0.f, 0.f, 0.f};

    for (int kb = 0; kb < K; kb += 32) {
        short8 a0 = *(const short8*)&A[(size_t)(m0 + tr) * K + kb + tc];
        short8 b0 = *(const short8*)&Bt[(size_t)(n0 + tr) * K + kb + tc];
        short8 b1 = *(const short8*)&Bt[(size_t)(n0 + 64 + tr) * K + kb + tc];
        __syncthreads();
        *(short8*)&As[tr][tc] = a0;
        *(short8*)&Bs[tr][tc] = b0;
        *(short8*)&Bs[64 + tr][tc] = b1;
        __syncthreads();
        short8 af[2], bf[4];
#pragma unroll
        for (int mt = 0; mt < 2; mt++) af[mt] = *(const short8*)&As[wm + mt * 16 + cc][g * 8];
#pragma unroll
        for (int nt = 0; nt < 4; nt++) bf[nt] = *(const short8*)&Bs[wn + nt * 16 + cc][g * 8];
#pragma unroll
        for (int mt = 0; mt < 2; mt++)
#pragma unroll
            for (int nt = 0; nt < 4; nt++)
                acc[mt][nt] = MFMA16(af[mt], bf[nt], acc[mt][nt]);
    }

#pragma unroll
    for (int mt = 0; mt < 2; mt++) {
        int rl = wm + mt * 16 + g * 4;
#pragma unroll
        for (int nt = 0; nt < 4; nt++) {
            int n = n0 + wn + nt * 16 + cc;
            float bb = bias[n];
#pragma unroll
            for (int r = 0; r < 4; r++)
                outf[(size_t)(m0 + rl + r) * 1024 + n] = scrub(acc[mt][nt][r] + bb);
        }
    }
}

// ---------------------------------------------------------------------------
// qe_srel, output-tile-oriented.  Block = (k-tile 128, q-tile 128, bh).
// Srel[q][k] = L: QE[q][1023-q+k]   if k <= 2q-1023        (k <= q region)
//              0                    if k == q+1
//              U: QE[q+1][k-q-2]    if q+2 <= k <= 2q+3
// In skewed coords both bands stage at Lds[prow][pm+prow-127] and read back
// at Lds[q-q0][k-k0].  Phase L: A rows q0.., B rows m0=896+k0-q0.
// Phase U: A rows q0+1.., B rows m0=k0-q0-129.  Coalesced permuted stores.
// ---------------------------------------------------------------------------
__global__ __launch_bounds__(256) void qe_srel(
    const u16* __restrict__ qh, const u16* __restrict__ eb, u16* __restrict__ SrelP)
{
    __shared__ u16 Lds[128][132];
    int k0 = blockIdx.x * 128, q0 = blockIdx.y * 128, bh = blockIdx.z;
    const u16* Q = qh + (size_t)bh * 65536;
    u16* S = SrelP + (size_t)bh * 1048576;
    int tid = threadIdx.x;
    int w = tid >> 6, lane = tid & 63, g = lane >> 4, cc = lane & 15;
    int wm = (w >> 1) * 64, wn = (w & 1) * 64;

    bool doL = (k0 <= 2 * q0 + 254 - 1023);
    bool doU = (k0 + 127 >= q0 + 2) && (k0 <= 2 * (q0 + 127) + 3);

    u16 cvv[2][32];
#pragma unroll
    for (int j = 0; j < 2; j++)
#pragma unroll
        for (int t = 0; t < 32; t++) cvv[j][t] = 0;

    for (int phase = 0; phase < 2; phase++) {
        if (phase == 0 && !doL) continue;
        if (phase == 1 && !doU) continue;
        int rowbase = q0 + phase;                       // L: q0,  U: q0+1
        int M0 = (phase == 0) ? (896 + k0 - q0) : (k0 - q0 - 129);

        // 128x256 QE rect, 2 column sub-passes of 128; wave tile 64x64.
#pragma unroll
        for (int p = 0; p < 2; p++) {
            f32x4 acc[4][4];
#pragma unroll
            for (int i = 0; i < 4; i++)
#pragma unroll
                for (int j = 0; j < 4; j++) acc[i][j] = (f32x4){0.f, 0.f, 0.f, 0.f};
            short8 af[4][2], bf[4][2];
#pragma unroll
            for (int mt = 0; mt < 4; mt++) {
                int row = rowbase + wm + mt * 16 + cc;
                row = min(row, 1023);
#pragma unroll
                for (int kf = 0; kf < 2; kf++)
                    af[mt][kf] = *(const short8*)&Q[(size_t)row * 64 + kf * 32 + g * 8];
            }
#pragma unroll
            for (int nt = 0; nt < 4; nt++) {
                int m = M0 + p * 128 + wn + nt * 16 + cc;
                m = min(max(m, 0), 1023);
#pragma unroll
                for (int kf = 0; kf < 2; kf++)
                    bf[nt][kf] = *(const short8*)&eb[(size_t)m * 64 + kf * 32 + g * 8];
            }
#pragma unroll
            for (int mt = 0; mt < 4; mt++)
#pragma unroll
                for (int nt = 0; nt < 4; nt++) {
                    acc[mt][nt] = MFMA16(af[mt][0], bf[nt][0], acc[mt][nt]);
                    acc[mt][nt] = MFMA16(af[mt][1], bf[nt][1], acc[mt][nt]);
                }
            // stage skewed: col = pm + prow - 127
#pragma unroll
            for (int mt = 0; mt < 4; mt++)
#pragma unroll
                for (int nt = 0; nt < 4; nt++)
#pragma unroll
                    for (int r = 0; r < 4; r++) {
                        int prow = wm + mt * 16 + g * 4 + r;
                        int col = p * 128 + wn + nt * 16 + cc + prow - 127;
                        if ((unsigned)col < 128u)
                            Lds[prow][col] = f2bf(acc[mt][nt][r]);
                    }
        }
        __syncthreads();
        // read back & select
#pragma unroll
        for (int j = 0; j < 2; j++) {
            int st = w * 2 + j;
#pragma unroll
            for (int idx = 0; idx < 32; idx++) {
                int nt = idx >> 2, r = idx & 3;
                int q = q0 + st * 16 + g * 4 + r;
                int k = k0 + nt * 16 + cc;
                u16 v = Lds[st * 16 + g * 4 + r][nt * 16 + cc];
                if (phase == 0)
                    cvv[j][idx] = (k <= 2 * q - 1023) ? v : (u16)0;
                else if (k >= q + 2 && k <= 2 * q + 3)
                    cvv[j][idx] = v;
            }
        }
        __syncthreads();
    }

    // coalesced permuted stores: per subtile, lane writes 32 contiguous u16
#pragma unroll
    for (int j = 0; j < 2; j++) {
        size_t base = ((size_t)((q0 >> 4) + w * 2 + j) << 14) |
                      ((size_t)(k0 >> 7) << 11) | ((size_t)(g * 16 + cc) * 32);
#pragma unroll
        for (int t = 0; t < 4; t++) {
            short8 pk;
#pragma unroll
            for (int u = 0; u < 8; u++) pk[u] = (short)cvv[j][t * 8 + u];
            *(short8*)&S[base + t * 8] = pk;
        }
    }
}

// ---------------------------------------------------------------------------
// Flash attention: grid (16, 64).  Block = 64 Q-rows, wave owns 16.
// No barriers (Plds wave-private).  Srel via permuted coalesced 16B loads.
// ctx out bf16 (b, l, h*64+d).
// ---------------------------------------------------------------------------
__global__ __launch_bounds__(256) void flash(
    const u16* __restrict__ qh, const u16* __restrict__ kh,
    const u16* __restrict__ vht, const u16* __restrict__ SrelP,
    u16* __restrict__ ctx)
{
    __shared__ u16 Plds[4][16][136];
    int qt = blockIdx.x, bh = blockIdx.y;
    int w = threadIdx.x >> 6, lane = threadIdx.x & 63, g = lane >> 4, cc = lane & 15;
    const u16* Q = qh + (size_t)bh * 65536;
    const u16* Kp = kh + (size_t)bh * 65536;
    const u16* Vp = vht + (size_t)bh * 65536;
    const u16* Sp = SrelP + (size_t)bh * 1048576 +
                    ((size_t)(((qt * 4 + w) * 32 + g) * 16 + cc)) * 32;
    int q0 = qt * 64 + w * 16;

    short8 qf[2];
#pragma unroll
    for (int ks = 0; ks < 2; ks++)
        qf[ks] = *(const short8*)&Q[(size_t)(q0 + cc) * 64 + ks * 32 + g * 8];

    float mi[4], li[4];
    f32x4 O[4];
#pragma unroll
    for (int r = 0; r < 4; r++) { mi[r] = -1e30f; li[r] = 0.f; }
#pragma unroll
    for (int d = 0; d < 4; d++) O[d] = (f32x4){0.f, 0.f, 0.f, 0.f};

    const float LOG2E = 1.44269504088896f;

    for (int kt = 0; kt < 8; kt++) {
        int k0 = kt * 128;
        u16 cv[32];
        *(short8*)&cv[0]  = *(const short8*)&Sp[kt * 2048 + 0];
        *(short8*)&cv[8]  = *(const short8*)&Sp[kt * 2048 + 8];
        *(short8*)&cv[16] = *(const short8*)&Sp[kt * 2048 + 16];
        *(short8*)&cv[24] = *(const short8*)&Sp[kt * 2048 + 24];

        f32x4 sc[8];
#pragma unroll
        for (int nt = 0; nt < 8; nt++) sc[nt] = (f32x4){0.f, 0.f, 0.f, 0.f};
#pragma unroll
        for (int nt = 0; nt < 8; nt++) {
            short8 b0 = *(const short8*)&Kp[(size_t)(k0 + nt * 16 + cc) * 64 + g * 8];
            short8 b1 = *(const short8*)&Kp[(size_t)(k0 + nt * 16 + cc) * 64 + 32 + g * 8];
            sc[nt] = MFMA16(qf[0], b0, sc[nt]);
            sc[nt] = MFMA16(qf[1], b1, sc[nt]);
        }

#pragma unroll
        for (int nt = 0; nt < 8; nt++)
#pragma unroll
            for (int r = 0; r < 4; r++)
                sc[nt][r] = (sc[nt][r] + bf2f(cv[nt * 4 + r])) * 0.125f;

#pragma unroll
        for (int r = 0; r < 4; r++) {
            float mx = sc[0][r];
#pragma unroll
            for (int nt = 1; nt < 8; nt++) mx = fmaxf(mx, sc[nt][r]);
            mx = fmaxf(mx, __shfl_xor(mx, 1));
            mx = fmaxf(mx, __shfl_xor(mx, 2));
            mx = fmaxf(mx, __shfl_xor(mx, 4));
            mx = fmaxf(mx, __shfl_xor(mx, 8));
            float mnew = fmaxf(mi[r], mx);
            float alpha = exp2f((mi[r] - mnew) * LOG2E);
            mi[r] = mnew;
            float rs = 0.f;
#pragma unroll
            for (int nt = 0; nt < 8; nt++) {
                float p = exp2f((sc[nt][r] - mnew) * LOG2E);
                sc[nt][r] = p;
                rs += p;
            }
            rs += __shfl_xor(rs, 1);
            rs += __shfl_xor(rs, 2);
            rs += __shfl_xor(rs, 4);
            rs += __shfl_xor(rs, 8);
            li[r] = li[r] * alpha + rs;
#pragma unroll
            for (int d = 0; d < 4; d++) O[d][r] *= alpha;
        }

#pragma unroll
        for (int nt = 0; nt < 8; nt++)
#pragma unroll
            for (int r = 0; r < 4; r++)
                Plds[w][g * 4 + r][nt * 16 + cc] = f2bf(sc[nt][r]);

#pragma unroll
        for (int ks = 0; ks < 4; ks++) {
            short8 a = *(const short8*)&Plds[w][cc][ks * 32 + g * 8];
#pragma unroll
            for (int d = 0; d < 4; d++) {
                short8 vb = *(const short8*)&Vp[(size_t)(d * 16 + cc) * 1024 + k0 + ks * 32 + g * 8];
                O[d] = MFMA16(a, vb, O[d]);
            }
        }
    }

    int b_ = bh >> 4, h_ = bh & 15;
#pragma unroll
    for (int d = 0; d < 4; d++)
#pragma unroll
        for (int r = 0; r < 4; r++) {
            int l_ = q0 + g * 4 + r;
            ctx[((size_t)b_ * 1024 + l_) * 1024 + h_ * 64 + d * 16 + cc] =
                f2bf(O[d][r] / li[r]);
        }
}

// ---------------------------------------------------------------------------
extern "C" void kernel_launch(void* const* d_in, const int* in_sizes, int n_in,
                              void* d_out, int out_size, void* d_ws, size_t ws_size,
                              hipStream_t stream)
{
    // Identify fp32 inputs by SIZE (robust to the bool mask's representation).
    const float *k_in = nullptr, *v_in = nullptr, *q_in = nullptr, *E = nullptr;
    const float* W[4] = {nullptr, nullptr, nullptr, nullptr};
    const float* bs[4] = {nullptr, nullptr, nullptr, nullptr};
    int nqkv = 0, nW = 0, nb = 0;
    for (int i = 0; i < n_in; i++) {
        int s = in_sizes[i];
        const float* p = (const float*)d_in[i];
        if (s == 4194304) {
            if (nqkv == 0) k_in = p; else if (nqkv == 1) v_in = p; else if (nqkv == 2) q_in = p;
            nqkv++;
        } else if (s == 131072) {
            E = p;
        } else if (s == 1048576) {
            if (nW < 4) W[nW] = p;
            nW++;
        } else if (s == 1024) {
            if (nb < 4) bs[nb] = p;
            nb++;
        }
    }

    char* ws = (char*)d_ws;
    u16* Wt   = (u16*)ws;                     // 8 MB
    u16* khp  = (u16*)(ws + (8u << 20));      // 8 MB  (b,h,l,d)
    u16* vhtp = (u16*)(ws + (16u << 20));     // 8 MB  (b,h,d,l)
    u16* qhp  = (u16*)(ws + (24u << 20));     // 8 MB  (b,h,l,d)
    u16* ctxp = (u16*)(ws + (32u << 20));     // 8 MB  (b,l,h*d) bf16
    u16* eb   = (u16*)(ws + (40u << 20));     // 128 KB bf16 e slice
    u16* Srel = (u16*)(ws + (48u << 20));     // 128 MB permuted -> 176 MB

    const size_t M1 = 1048576;
    transpose4<<<dim3(32, 32, 4), 256, 0, stream>>>(W[0], W[1], W[2], W[3], Wt);
    ecvt<<<dim3(64), 256, 0, stream>>>(E + 65536, eb);
    gemm_qkv<<<dim3(8, 32, 3), 256, 0, stream>>>(k_in, v_in, q_in, Wt,
                                                 bs[0], bs[1], bs[2],
                                                 khp, vhtp, qhp);
    qe_srel<<<dim3(8, 8, 64), 256, 0, stream>>>(qhp, eb, Srel);
    flash<<<dim3(16, 64), 256, 0, stream>>>(qhp, khp, vhtp, Srel, ctxp);
    gemm_out<<<dim3(8, 64), 256, 0, stream>>>(ctxp, Wt + 3 * M1, bs[3], (float*)d_out);
}

// Round 6
// 386.868 us; speedup vs baseline: 1.7134x; 1.6751x over previous
//
#include <hip/hip_runtime.h>
#include <stdint.h>

typedef unsigned short u16;
typedef __attribute__((ext_vector_type(8))) short short8;
typedef __attribute__((ext_vector_type(4))) float f32x4;
typedef __attribute__((ext_vector_type(4))) unsigned short u16x4;

#define MFMA16(a, b, c) __builtin_amdgcn_mfma_f32_16x16x32_bf16((a), (b), (c), 0, 0, 0)

__device__ __forceinline__ float bf2f(u16 u) {
    union { uint32_t i; float f; } v;
    v.i = ((uint32_t)u) << 16;
    return v.f;
}
__device__ __forceinline__ u16 f2bf(float f) {  // round-to-nearest-even
    union { float f; uint32_t i; } v;
    v.f = f;
    uint32_t r = v.i + 0x7FFF + ((v.i >> 16) & 1);
    return (u16)(r >> 16);
}
__device__ __forceinline__ float scrub(float x) {  // bit-level Inf/NaN scrub
    union { float f; uint32_t i; } v;
    v.f = x;
    return ((v.i & 0x7F800000u) == 0x7F800000u) ? 0.f : x;
}

// ---------------------------------------------------------------------------
// Transpose 4 fp32 weight matrices (1024x1024) -> bf16 Wt[n][k] = W[k][n]
// ---------------------------------------------------------------------------
__global__ __launch_bounds__(256) void transpose4(
    const float* __restrict__ W0, const float* __restrict__ W1,
    const float* __restrict__ W2, const float* __restrict__ W3,
    u16* __restrict__ out)
{
    __shared__ u16 t[32][33];
    int z = blockIdx.z;
    const float* W = (z == 0) ? W0 : (z == 1) ? W1 : (z == 2) ? W2 : W3;
    u16* o = out + (size_t)z * 1048576;
    int tx = threadIdx.x & 31, ty = threadIdx.x >> 5;
    int x = blockIdx.x * 32 + tx;
    int yb = blockIdx.y * 32;
#pragma unroll
    for (int j = 0; j < 4; j++)
        t[ty + j * 8][tx] = f2bf(W[(size_t)(yb + ty + j * 8) * 1024 + x]);
    __syncthreads();
    int xo = yb + tx;
    int yob = blockIdx.x * 32;
#pragma unroll
    for (int j = 0; j < 4; j++)
        o[(size_t)(yob + ty + j * 8) * 1024 + xo] = t[tx][ty + j * 8];
}

// ---------------------------------------------------------------------------
// Convert E-slice (1024x64 fp32) to bf16.
// ---------------------------------------------------------------------------
__global__ __launch_bounds__(256) void ecvt(
    const float* __restrict__ e, u16* __restrict__ eb)
{
    int i = (blockIdx.x * 256 + threadIdx.x) * 4;
    f32x4 v = *(const f32x4*)&e[i];
    u16x4 o;
#pragma unroll
    for (int r = 0; r < 4; r++) o[r] = f2bf(v[r]);
    *(u16x4*)&eb[i] = o;
}

// ---------------------------------------------------------------------------
// Convert k,v,q (4096x1024 fp32 each) to bf16 once.  grid (4096, 3).
// ---------------------------------------------------------------------------
__global__ __launch_bounds__(256) void cvt3(
    const float* __restrict__ a0, const float* __restrict__ a1,
    const float* __restrict__ a2, u16* __restrict__ o0,
    u16* __restrict__ o1, u16* __restrict__ o2)
{
    int z = blockIdx.y;
    const float* a = (z == 0) ? a0 : (z == 1) ? a1 : a2;
    u16* o = (z == 0) ? o0 : (z == 1) ? o1 : o2;
    int i = (blockIdx.x * 256 + threadIdx.x) * 4;
    f32x4 v = *(const f32x4*)&a[i];
    u16x4 p;
#pragma unroll
    for (int r = 0; r < 4; r++) p[r] = f2bf(v[r]);
    *(u16x4*)&o[i] = p;
}

// ---------------------------------------------------------------------------
// Merged K/V/Q projection GEMM (all-bf16): grid (8, 32, 3).
// C(M,N) = A(M,K)*Wt_z(N,K)^T + bias_z.  128x128 tile, 4 waves.
// z==1 (V): out (b,h,d,l); else (b,h,l,d).
// ---------------------------------------------------------------------------
__global__ __launch_bounds__(256) void gemm_qkv(
    const u16* __restrict__ A0, const u16* __restrict__ A1,
    const u16* __restrict__ A2, const u16* __restrict__ Wt,
    const float* __restrict__ bi0, const float* __restrict__ bi1,
    const float* __restrict__ bi2, u16* __restrict__ khp,
    u16* __restrict__ vhtp, u16* __restrict__ qhp)
{
    __shared__ u16 As[128][40];
    __shared__ u16 Bs[128][40];
    const int K = 1024;
    int z = blockIdx.z;
    const u16* A = (z == 0) ? A0 : (z == 1) ? A1 : A2;
    const float* bias = (z == 0) ? bi0 : (z == 1) ? bi1 : bi2;
    const u16* Bt = Wt + (size_t)z * 1048576;
    u16* outb = (z == 0) ? khp : (z == 1) ? vhtp : qhp;

    int n0 = blockIdx.x * 128, m0 = blockIdx.y * 128;
    int tid = threadIdx.x;
    int w = tid >> 6, lane = tid & 63, g = lane >> 4, cc = lane & 15;
    int wm = (w >> 1) * 64, wn = (w & 1) * 64;
    int tr = tid >> 2, tc = (tid & 3) * 8;

    f32x4 acc[4][4];
#pragma unroll
    for (int i = 0; i < 4; i++)
#pragma unroll
        for (int j = 0; j < 4; j++) acc[i][j] = (f32x4){0.f, 0.f, 0.f, 0.f};

    for (int kb = 0; kb < K; kb += 32) {
        short8 a0 = *(const short8*)&A[(size_t)(m0 + tr) * K + kb + tc];
        short8 a1 = *(const short8*)&A[(size_t)(m0 + 64 + tr) * K + kb + tc];
        short8 b0 = *(const short8*)&Bt[(size_t)(n0 + tr) * K + kb + tc];
        short8 b1 = *(const short8*)&Bt[(size_t)(n0 + 64 + tr) * K + kb + tc];
        __syncthreads();
        *(short8*)&As[tr][tc] = a0;
        *(short8*)&As[64 + tr][tc] = a1;
        *(short8*)&Bs[tr][tc] = b0;
        *(short8*)&Bs[64 + tr][tc] = b1;
        __syncthreads();
        short8 af[4], bf[4];
#pragma unroll
        for (int mt = 0; mt < 4; mt++) af[mt] = *(const short8*)&As[wm + mt * 16 + cc][g * 8];
#pragma unroll
        for (int nt = 0; nt < 4; nt++) bf[nt] = *(const short8*)&Bs[wn + nt * 16 + cc][g * 8];
#pragma unroll
        for (int mt = 0; mt < 4; mt++)
#pragma unroll
            for (int nt = 0; nt < 4; nt++)
                acc[mt][nt] = MFMA16(af[mt], bf[nt], acc[mt][nt]);
    }

#pragma unroll
    for (int mt = 0; mt < 4; mt++) {
        int rl = wm + mt * 16 + g * 4;
#pragma unroll
        for (int nt = 0; nt < 4; nt++) {
            int n = n0 + wn + nt * 16 + cc;
            float bb = bias[n];
            if (z == 1) {  // V: (b,h,d,l)
                int m = m0 + rl;
                int b_ = m >> 10, l_ = m & 1023, h_ = n >> 6, d_ = n & 63;
                u16x4 pk;
#pragma unroll
                for (int r = 0; r < 4; r++) pk[r] = f2bf(scrub(acc[mt][nt][r] + bb));
                *(u16x4*)&outb[((size_t)(b_ * 16 + h_) * 64 + d_) * 1024 + l_] = pk;
            } else {  // K/Q: (b,h,l,d)
#pragma unroll
                for (int r = 0; r < 4; r++) {
                    int m = m0 + rl + r;
                    int b_ = m >> 10, l_ = m & 1023, h_ = n >> 6, d_ = n & 63;
                    outb[((size_t)(b_ * 16 + h_) * 1024 + l_) * 64 + d_] =
                        f2bf(scrub(acc[mt][nt][r] + bb));
                }
            }
        }
    }
}

// ---------------------------------------------------------------------------
// Final GEMM: out(4096,1024) = ctx(4096,1024 bf16)*Wo^T + bo.  64x128 tiles,
// grid (8, 64).  fp32 output.
// ---------------------------------------------------------------------------
__global__ __launch_bounds__(256) void gemm_out(
    const u16* __restrict__ A, const u16* __restrict__ Bt,
    const float* __restrict__ bias, float* __restrict__ outf)
{
    __shared__ u16 As[64][40];
    __shared__ u16 Bs[128][40];
    const int K = 1024;
    int n0 = blockIdx.x * 128, m0 = blockIdx.y * 64;
    int tid = threadIdx.x;
    int w = tid >> 6, lane = tid & 63, g = lane >> 4, cc = lane & 15;
    int wm = (w >> 1) * 32, wn = (w & 1) * 64;
    int tr = tid >> 2, tc = (tid & 3) * 8;

    f32x4 acc[2][4];
#pragma unroll
    for (int i = 0; i < 2; i++)
#pragma unroll
        for (int j = 0; j < 4; j++) acc[i][j] = (f32x4){0.f, 0.f, 0.f, 0.f};

    for (int kb = 0; kb < K; kb += 32) {
        short8 a0 = *(const short8*)&A[(size_t)(m0 + tr) * K + kb + tc];
        short8 b0 = *(const short8*)&Bt[(size_t)(n0 + tr) * K + kb + tc];
        short8 b1 = *(const short8*)&Bt[(size_t)(n0 + 64 + tr) * K + kb + tc];
        __syncthreads();
        *(short8*)&As[tr][tc] = a0;
        *(short8*)&Bs[tr][tc] = b0;
        *(short8*)&Bs[64 + tr][tc] = b1;
        __syncthreads();
        short8 af[2], bf[4];
#pragma unroll
        for (int mt = 0; mt < 2; mt++) af[mt] = *(const short8*)&As[wm + mt * 16 + cc][g * 8];
#pragma unroll
        for (int nt = 0; nt < 4; nt++) bf[nt] = *(const short8*)&Bs[wn + nt * 16 + cc][g * 8];
#pragma unroll
        for (int mt = 0; mt < 2; mt++)
#pragma unroll
            for (int nt = 0; nt < 4; nt++)
                acc[mt][nt] = MFMA16(af[mt], bf[nt], acc[mt][nt]);
    }

#pragma unroll
    for (int mt = 0; mt < 2; mt++) {
        int rl = wm + mt * 16 + g * 4;
#pragma unroll
        for (int nt = 0; nt < 4; nt++) {
            int n = n0 + wn + nt * 16 + cc;
            float bb = bias[n];
#pragma unroll
            for (int r = 0; r < 4; r++)
                outf[(size_t)(m0 + rl + r) * 1024 + n] = scrub(acc[mt][nt][r] + bb);
        }
    }
}

// ---------------------------------------------------------------------------
// Masked QE GEMM, natural layout: QEm[bh][q][m] = (m<=q) ? qh[q].e[m] : 0.
// grid (8 m-tiles, 8 q-tiles, 64 bh).  Plain coalesced epilogue; flash does
// the skew-gather.  K=64.
// ---------------------------------------------------------------------------
__global__ __launch_bounds__(256) void qe_gemm(
    const u16* __restrict__ qh, const u16* __restrict__ eb, u16* __restrict__ QEm)
{
    __shared__ u16 As[128][40];
    __shared__ u16 Bs[128][40];
    int mb = blockIdx.x * 128;
    int qb = blockIdx.y * 128;
    int bh = blockIdx.z;
    const u16* A = qh + (size_t)bh * 65536;
    u16* O = QEm + (size_t)bh * 1048576;
    int tid = threadIdx.x;
    int w = tid >> 6, lane = tid & 63, g = lane >> 4, cc = lane & 15;
    int wm = (w >> 1) * 64, wn = (w & 1) * 64;
    int tr = tid >> 2, tc = (tid & 3) * 8;

    f32x4 acc[4][4];
#pragma unroll
    for (int i = 0; i < 4; i++)
#pragma unroll
        for (int j = 0; j < 4; j++) acc[i][j] = (f32x4){0.f, 0.f, 0.f, 0.f};

#pragma unroll
    for (int kb = 0; kb < 64; kb += 32) {
        short8 a0 = *(const short8*)&A[(size_t)(qb + tr) * 64 + kb + tc];
        short8 a1 = *(const short8*)&A[(size_t)(qb + 64 + tr) * 64 + kb + tc];
        short8 b0 = *(const short8*)&eb[(size_t)(mb + tr) * 64 + kb + tc];
        short8 b1 = *(const short8*)&eb[(size_t)(mb + 64 + tr) * 64 + kb + tc];
        __syncthreads();
        *(short8*)&As[tr][tc] = a0;
        *(short8*)&As[64 + tr][tc] = a1;
        *(short8*)&Bs[tr][tc] = b0;
        *(short8*)&Bs[64 + tr][tc] = b1;
        __syncthreads();
        short8 af[4], bf[4];
#pragma unroll
        for (int mt = 0; mt < 4; mt++) af[mt] = *(const short8*)&As[wm + mt * 16 + cc][g * 8];
#pragma unroll
        for (int nt = 0; nt < 4; nt++) bf[nt] = *(const short8*)&Bs[wn + nt * 16 + cc][g * 8];
#pragma unroll
        for (int mt = 0; mt < 4; mt++)
#pragma unroll
            for (int nt = 0; nt < 4; nt++)
                acc[mt][nt] = MFMA16(af[mt], bf[nt], acc[mt][nt]);
    }

#pragma unroll
    for (int mt = 0; mt < 4; mt++)
#pragma unroll
        for (int nt = 0; nt < 4; nt++)
#pragma unroll
            for (int r = 0; r < 4; r++) {
                int qi = qb + wm + mt * 16 + g * 4 + r;
                int mm = mb + wn + nt * 16 + cc;
                u16 v = (mm <= qi) ? f2bf(scrub(acc[mt][nt][r])) : (u16)0;
                O[(size_t)qi * 1024 + mm] = v;
            }
}

// ---------------------------------------------------------------------------
// Flash attention: grid (16, 64).  Block = 64 Q-rows, wave owns 16, no
// barriers.  Srel gathered per-element from natural-layout masked QE:
//   k<=q   -> QEm[q][1023+k-q]
//   k==q+1 -> 0
//   k>=q+2 -> QEm[q+1][k-q-2]
// ctx out bf16 (b, l, h*64+d).
// ---------------------------------------------------------------------------
__global__ __launch_bounds__(256) void flash(
    const u16* __restrict__ qh, const u16* __restrict__ kh,
    const u16* __restrict__ vht, const u16* __restrict__ QEm,
    u16* __restrict__ ctx)
{
    __shared__ u16 Plds[4][16][136];
    int qt = blockIdx.x, bh = blockIdx.y;
    int w = threadIdx.x >> 6, lane = threadIdx.x & 63, g = lane >> 4, cc = lane & 15;
    const u16* Q = qh + (size_t)bh * 65536;
    const u16* Kp = kh + (size_t)bh * 65536;
    const u16* Vp = vht + (size_t)bh * 65536;
    const u16* QE = QEm + (size_t)bh * 1048576;
    int q0 = qt * 64 + w * 16;

    short8 qf[2];
#pragma unroll
    for (int ks = 0; ks < 2; ks++)
        qf[ks] = *(const short8*)&Q[(size_t)(q0 + cc) * 64 + ks * 32 + g * 8];

    float mi[4], li[4];
    f32x4 O[4];
#pragma unroll
    for (int r = 0; r < 4; r++) { mi[r] = -1e30f; li[r] = 0.f; }
#pragma unroll
    for (int d = 0; d < 4; d++) O[d] = (f32x4){0.f, 0.f, 0.f, 0.f};

    const float LOG2E = 1.44269504088896f;

    for (int kt = 0; kt < 8; kt++) {
        int k0 = kt * 128;
        // Srel gather (issued first; independent of the MFMAs below)
        u16 cv[32];
#pragma unroll
        for (int r = 0; r < 4; r++) {
            int q = q0 + g * 4 + r;
#pragma unroll
            for (int nt = 0; nt < 8; nt++) {
                int k = k0 + nt * 16 + cc;
                bool lower = (k <= q);
                int row = lower ? q : (q + 1);
                int col = lower ? (1023 + k - q) : (k - q - 2);
                col = (col < 0) ? 0 : col;
                u16 v = QE[(size_t)row * 1024 + col];
                cv[nt * 4 + r] = (k == q + 1) ? (u16)0 : v;
            }
        }

        f32x4 sc[8];
#pragma unroll
        for (int nt = 0; nt < 8; nt++) sc[nt] = (f32x4){0.f, 0.f, 0.f, 0.f};
#pragma unroll
        for (int nt = 0; nt < 8; nt++) {
            short8 b0 = *(const short8*)&Kp[(size_t)(k0 + nt * 16 + cc) * 64 + g * 8];
            short8 b1 = *(const short8*)&Kp[(size_t)(k0 + nt * 16 + cc) * 64 + 32 + g * 8];
            sc[nt] = MFMA16(qf[0], b0, sc[nt]);
            sc[nt] = MFMA16(qf[1], b1, sc[nt]);
        }

#pragma unroll
        for (int nt = 0; nt < 8; nt++)
#pragma unroll
            for (int r = 0; r < 4; r++)
                sc[nt][r] = (sc[nt][r] + bf2f(cv[nt * 4 + r])) * 0.125f;

#pragma unroll
        for (int r = 0; r < 4; r++) {
            float mx = sc[0][r];
#pragma unroll
            for (int nt = 1; nt < 8; nt++) mx = fmaxf(mx, sc[nt][r]);
            mx = fmaxf(mx, __shfl_xor(mx, 1));
            mx = fmaxf(mx, __shfl_xor(mx, 2));
            mx = fmaxf(mx, __shfl_xor(mx, 4));
            mx = fmaxf(mx, __shfl_xor(mx, 8));
            float mnew = fmaxf(mi[r], mx);
            float alpha = exp2f((mi[r] - mnew) * LOG2E);
            mi[r] = mnew;
            float rs = 0.f;
#pragma unroll
            for (int nt = 0; nt < 8; nt++) {
                float p = exp2f((sc[nt][r] - mnew) * LOG2E);
                sc[nt][r] = p;
                rs += p;
            }
            rs += __shfl_xor(rs, 1);
            rs += __shfl_xor(rs, 2);
            rs += __shfl_xor(rs, 4);
            rs += __shfl_xor(rs, 8);
            li[r] = li[r] * alpha + rs;
#pragma unroll
            for (int d = 0; d < 4; d++) O[d][r] *= alpha;
        }

#pragma unroll
        for (int nt = 0; nt < 8; nt++)
#pragma unroll
            for (int r = 0; r < 4; r++)
                Plds[w][g * 4 + r][nt * 16 + cc] = f2bf(sc[nt][r]);

#pragma unroll
        for (int ks = 0; ks < 4; ks++) {
            short8 a = *(const short8*)&Plds[w][cc][ks * 32 + g * 8];
#pragma unroll
            for (int d = 0; d < 4; d++) {
                short8 vb = *(const short8*)&Vp[(size_t)(d * 16 + cc) * 1024 + k0 + ks * 32 + g * 8];
                O[d] = MFMA16(a, vb, O[d]);
            }
        }
    }

    int b_ = bh >> 4, h_ = bh & 15;
#pragma unroll
    for (int d = 0; d < 4; d++)
#pragma unroll
        for (int r = 0; r < 4; r++) {
            int l_ = q0 + g * 4 + r;
            ctx[((size_t)b_ * 1024 + l_) * 1024 + h_ * 64 + d * 16 + cc] =
                f2bf(O[d][r] / li[r]);
        }
}

// ---------------------------------------------------------------------------
extern "C" void kernel_launch(void* const* d_in, const int* in_sizes, int n_in,
                              void* d_out, int out_size, void* d_ws, size_t ws_size,
                              hipStream_t stream)
{
    // Identify fp32 inputs by SIZE (robust to the bool mask's representation).
    const float *k_in = nullptr, *v_in = nullptr, *q_in = nullptr, *E = nullptr;
    const float* W[4] = {nullptr, nullptr, nullptr, nullptr};
    const float* bs[4] = {nullptr, nullptr, nullptr, nullptr};
    int nqkv = 0, nW = 0, nb = 0;
    for (int i = 0; i < n_in; i++) {
        int s = in_sizes[i];
        const float* p = (const float*)d_in[i];
        if (s == 4194304) {
            if (nqkv == 0) k_in = p; else if (nqkv == 1) v_in = p; else if (nqkv == 2) q_in = p;
            nqkv++;
        } else if (s == 131072) {
            E = p;
        } else if (s == 1048576) {
            if (nW < 4) W[nW] = p;
            nW++;
        } else if (s == 1024) {
            if (nb < 4) bs[nb] = p;
            nb++;
        }
    }

    char* ws = (char*)d_ws;
    u16* Wt   = (u16*)ws;                     // 8 MB
    u16* khp  = (u16*)(ws + (8u << 20));      // 8 MB  (b,h,l,d)
    u16* vhtp = (u16*)(ws + (16u << 20));     // 8 MB  (b,h,d,l)
    u16* qhp  = (u16*)(ws + (24u << 20));     // 8 MB  (b,h,l,d)
    u16* ctxp = (u16*)(ws + (32u << 20));     // 8 MB  (b,l,h*d) bf16
    u16* eb   = (u16*)(ws + (40u << 20));     // 128 KB bf16 e slice
    u16* kb   = (u16*)(ws + (48u << 20));     // 8 MB bf16 k   (dead after qkv)
    u16* vb   = (u16*)(ws + (56u << 20));     // 8 MB bf16 v   (dead after qkv)
    u16* qb   = (u16*)(ws + (64u << 20));     // 8 MB bf16 q   (dead after qkv)
    u16* QEm  = (u16*)(ws + (48u << 20));     // 128 MB, overlaps kb/vb/qb -> 176 MB

    const size_t M1 = 1048576;
    transpose4<<<dim3(32, 32, 4), 256, 0, stream>>>(W[0], W[1], W[2], W[3], Wt);
    ecvt<<<dim3(64), 256, 0, stream>>>(E + 65536, eb);
    cvt3<<<dim3(4096, 3), 256, 0, stream>>>(k_in, v_in, q_in, kb, vb, qb);
    gemm_qkv<<<dim3(8, 32, 3), 256, 0, stream>>>(kb, vb, qb, Wt,
                                                 bs[0], bs[1], bs[2],
                                                 khp, vhtp, qhp);
    qe_gemm<<<dim3(8, 8, 64), 256, 0, stream>>>(qhp, eb, QEm);
    flash<<<dim3(16, 64), 256, 0, stream>>>(qhp, khp, vhtp, QEm, ctxp);
    gemm_out<<<dim3(8, 64), 256, 0, stream>>>(ctxp, Wt + 3 * M1, bs[3], (float*)d_out);
}